// Round 4
// baseline (121.064 us; speedup 1.0000x reference)
//
#include <hip/hip_runtime.h>

// ButterflyRotation: 12 butterfly layers over rows of 4096 fp32.
// R4: 3-phase radix-16. Block=256 (4 waves), 2 rows, 32 KiB LDS, 2 barriers.
//   phase A: thread t owns e = 16t+k      (k=0..15)  -> layers 0-3  (in-reg)
//   phase B: thread t owns e = 256hi+16m+lo (m=0..15) -> layers 4-7  (in-reg)
//   phase C: thread t owns e = t+256m     (m=0..15)  -> layers 8-11 (in-reg)
// LDS slots XOR-swizzled; phase-B read/write hit the same per-thread slots,
// so only 2 __syncthreads total.

#define DIM    4096
#define LAYERS 12
#define BATCH  8192
#define NANG   2048

// element -> swizzled LDS slot (keeps quads contiguous for b128 writes)
__device__ __forceinline__ int perm(int e) {
    int Q = e >> 2;
    int g = ((Q >> 3) & 7) ^ ((Q >> 6) & 7);
    return (((Q ^ g) << 2) | (e & 3));
}

// butterfly angle sub-index for left element m at level j (stride 2^j)
__device__ __forceinline__ constexpr int inner_idx(int m, int j) {
    return ((m >> (j + 1)) << j) + (m & ((1 << j) - 1));
}

__device__ __forceinline__ void rot(float& xl, float& xr, float c, float s) {
    float nl = fmaf(s, xr, c * xl);
    float nr = fmaf(-s, xl, c * xr);
    xl = nl; xr = nr;
}

__global__ void __launch_bounds__(256) cs_kernel(const float* __restrict__ angles,
                                                 float2* __restrict__ cs, int n) {
    int i = blockIdx.x * blockDim.x + threadIdx.x;
    if (i < n) {
        float a = angles[i];
        cs[i] = make_float2(cosf(a), sinf(a));
    }
}

__global__ void __launch_bounds__(256, 4)
butterfly_kernel(const float* __restrict__ x, const float2* __restrict__ cs,
                 float* __restrict__ out) {
    __shared__ float lds[2 * DIM];          // 32 KiB: row0 | row1
    const int t = threadIdx.x;              // 0..255
    const long row0 = (long)blockIdx.x * 2;

    // ================= phase A: e = 16t + k =================
    float a0[16], a1[16];
    {
        const float* p0 = x + row0 * DIM + 16 * t;
        const float* p1 = p0 + DIM;
        #pragma unroll
        for (int q = 0; q < 4; ++q) {
            float4 v0 = *(const float4*)(p0 + 4 * q);
            float4 v1 = *(const float4*)(p1 + 4 * q);
            a0[4*q+0] = v0.x; a0[4*q+1] = v0.y; a0[4*q+2] = v0.z; a0[4*q+3] = v0.w;
            a1[4*q+0] = v1.x; a1[4*q+1] = v1.y; a1[4*q+2] = v1.z; a1[4*q+3] = v1.w;
        }
    }
    // layers 0..3: angle slice [8t, 8t+8) of each layer table
    #pragma unroll
    for (int l = 0; l < 4; ++l) {
        const float2* tl = cs + l * NANG + 8 * t;
        float4 cA = *(const float4*)(tl + 0);
        float4 cB = *(const float4*)(tl + 2);
        float4 cC = *(const float4*)(tl + 4);
        float4 cD = *(const float4*)(tl + 6);
        const float cc[8] = {cA.x, cA.z, cB.x, cB.z, cC.x, cC.z, cD.x, cD.z};
        const float ss[8] = {cA.y, cA.w, cB.y, cB.w, cC.y, cC.w, cD.y, cD.w};
        const int st = 1 << l;
        #pragma unroll
        for (int m = 0; m < 16; ++m) {
            if (!(m & st)) {
                const int ai = inner_idx(m, l);   // compile-time
                rot(a0[m], a0[m + st], cc[ai], ss[ai]);
                rot(a1[m], a1[m + st], cc[ai], ss[ai]);
            }
        }
    }
    // transpose-1 write: 4x ds_write_b128 per row, swizzled (8-group spread)
    #pragma unroll
    for (int q = 0; q < 4; ++q) {
        int Q  = 4 * t + q;
        int Qs = Q ^ ((Q >> 3) & 7) ^ ((Q >> 6) & 7);
        *(float4*)(lds + 4 * Qs)       = make_float4(a0[4*q], a0[4*q+1], a0[4*q+2], a0[4*q+3]);
        *(float4*)(lds + DIM + 4 * Qs) = make_float4(a1[4*q], a1[4*q+1], a1[4*q+2], a1[4*q+3]);
    }
    __syncthreads();

    // ================= phase B: e = 256*hi + 16*m + lo =================
    const int hi = t & 15, lo = t >> 4;
    float d0[16], d1[16];
    #pragma unroll
    for (int m = 0; m < 16; ++m) {
        const int p = perm(256 * hi + 16 * m + lo);   // 2-way banks (free)
        d0[m] = lds[p];
        d1[m] = lds[DIM + p];
    }
    // layers 4..7: a = 128*hi + lo + 16*inner(m, l-4)
    #pragma unroll
    for (int l = 4; l < 8; ++l) {
        const float2* tl = cs + l * NANG + 128 * hi + lo;
        const int j = l - 4, st = 1 << j;
        #pragma unroll
        for (int m = 0; m < 16; ++m) {
            if (!(m & st)) {
                float2 c = tl[16 * inner_idx(m, j)];
                rot(d0[m], d0[m + st], c.x, c.y);
                rot(d1[m], d1[m + st], c.x, c.y);
            }
        }
    }
    // transpose-2 write: SAME per-thread slots -> no barrier needed before
    #pragma unroll
    for (int m = 0; m < 16; ++m) {
        const int p = perm(256 * hi + 16 * m + lo);
        lds[p]       = d0[m];
        lds[DIM + p] = d1[m];
    }
    __syncthreads();

    // ================= phase C: e = t + 256*m =================
    float g0[16], g1[16];
    #pragma unroll
    for (int m = 0; m < 16; ++m) {
        const int p = perm(t + 256 * m);              // 2-way banks (free)
        g0[m] = lds[p];
        g1[m] = lds[DIM + p];
    }
    // layers 8..11: a = t + 256*inner(m, l-8)  (coalesced across lanes)
    #pragma unroll
    for (int l = 8; l < 12; ++l) {
        const float2* tl = cs + l * NANG + t;
        const int j = l - 8, st = 1 << j;
        #pragma unroll
        for (int m = 0; m < 16; ++m) {
            if (!(m & st)) {
                float2 c = tl[256 * inner_idx(m, j)];
                rot(g0[m], g0[m + st], c.x, c.y);
                rot(g1[m], g1[m + st], c.x, c.y);
            }
        }
    }
    // store: per instruction a wave writes 256B contiguous
    {
        float* o0 = out + row0 * DIM + t;
        float* o1 = o0 + DIM;
        #pragma unroll
        for (int m = 0; m < 16; ++m) {
            o0[256 * m] = g0[m];
            o1[256 * m] = g1[m];
        }
    }
}

extern "C" void kernel_launch(void* const* d_in, const int* in_sizes, int n_in,
                              void* d_out, int out_size, void* d_ws, size_t ws_size,
                              hipStream_t stream) {
    (void)in_sizes; (void)n_in; (void)out_size; (void)ws_size;
    const float* x      = (const float*)d_in[0];
    const float* angles = (const float*)d_in[1];
    float* out = (float*)d_out;
    float2* cs = (float2*)d_ws;   // 12*2048*8 B = 196 KiB scratch

    const int n = LAYERS * NANG;
    cs_kernel<<<(n + 255) / 256, 256, 0, stream>>>(angles, cs, n);
    butterfly_kernel<<<BATCH / 2, 256, 0, stream>>>(x, cs, out);
}

// Round 5
// 62.914 us; speedup vs baseline: 1.9243x; 1.9243x over previous
//
#include <hip/hip_runtime.h>

// ButterflyRotation: 12 butterfly layers over rows of 4096 fp32.
// R5: 3-phase radix-16 (R4 structure) + fully-coalesced memory:
//  - cos/sin table scattered into per-phase transposed layout T4[..][t]
//    so every angle load is lane-contiguous float4.
//  - x staged via global_load_lds (linear LDS dest, swizzled global src).
// Block=256 (4 waves), 2 rows, 32 KiB LDS, 3 barriers.
//   phase A: thread t owns e = 16t+k        -> layers 0-3  (in-reg)
//   phase B: thread t owns e = 256(t&15)+16m+(t>>4) -> layers 4-7
//   phase C: thread t owns e = t+256m       -> layers 8-11

#define DIM    4096
#define LAYERS 12
#define BATCH  8192
#define NANG   2048

// quad-level swizzle (involution: only bits 0-2 change)
__device__ __forceinline__ int swzQ(int Q) {
    return Q ^ ((Q >> 3) & 7) ^ ((Q >> 6) & 7);
}
// element -> swizzled LDS slot
__device__ __forceinline__ int perm(int e) {
    return (swzQ(e >> 2) << 2) | (e & 3);
}
// butterfly angle sub-index for left element m at level j (stride 2^j)
__device__ __forceinline__ constexpr int inner_idx(int m, int j) {
    return ((m >> (j + 1)) << j) + (m & ((1 << j) - 1));
}

__device__ __forceinline__ void rot(float& xl, float& xr, float c, float s) {
    float nl = fmaf(s, xr, c * xl);
    float nr = fmaf(-s, xl, c * xr);
    xl = nl; xr = nr;
}

// Build transposed cos/sin table:
//  region A (f4 idx [0,4096)):    TA[l][k2][t] = layer l,   angles 8t+2k2, 8t+2k2+1
//  region B (f4 idx [4096,8192)): TB[j][k2][t] = layer 4+j, angles 128(t&15)+(t>>4)+16*(2k2[, +1])
//  region C (f4 idx [8192,12288)):TC[j][k2][t] = layer 8+j, angles t+256*(2k2[, +1])
__global__ void __launch_bounds__(256) cs_kernel(const float* __restrict__ angles,
                                                 float2* __restrict__ T, int n) {
    int i = blockIdx.x * blockDim.x + threadIdx.x;
    if (i >= n) return;
    float a = angles[i];
    float c = cosf(a), s = sinf(a);
    int l = i >> 11, aa = i & 2047;
    int f4, half;
    if (l < 4) {
        int t = aa >> 3, k = aa & 7;
        f4 = (l * 4 + (k >> 1)) * 256 + t; half = k & 1;
    } else if (l < 8) {
        int hi = aa >> 7, k = (aa >> 4) & 7, lo = aa & 15;
        int t = hi + (lo << 4);
        f4 = 4096 + ((l - 4) * 4 + (k >> 1)) * 256 + t; half = k & 1;
    } else {
        int k = aa >> 8, t = aa & 255;
        f4 = 8192 + ((l - 8) * 4 + (k >> 1)) * 256 + t; half = k & 1;
    }
    T[f4 * 2 + half] = make_float2(c, s);
}

typedef unsigned int u32;

__global__ void __launch_bounds__(256, 4)
butterfly_kernel(const float* __restrict__ x, const float4* __restrict__ T4,
                 float* __restrict__ out) {
    __shared__ float lds[2 * DIM];          // 32 KiB: row0 | row1
    const int t = threadIdx.x;
    const int wave = t >> 6, lane = t & 63;
    const long row0 = (long)blockIdx.x * 2;

    // ---- stage-in: linear LDS dest, swizzled global source (involution) ----
    #pragma unroll
    for (int r = 0; r < 2; ++r) {
        const float* src = x + (row0 + r) * DIM;
        #pragma unroll
        for (int j = 0; j < 4; ++j) {
            const int qbase = (wave << 8) + (j << 6);      // wave-uniform
            const int g = swzQ(qbase + lane);              // global quad for this slot
            __builtin_amdgcn_global_load_lds(
                (const __attribute__((address_space(1))) u32*)(src + 4 * g),
                (__attribute__((address_space(3))) u32*)(lds + r * DIM + 4 * qbase),
                16, 0, 0);
        }
    }
    __syncthreads();

    // ================= phase A: e = 16t + k =================
    float a0[16], a1[16];
    int pa[4];
    #pragma unroll
    for (int q = 0; q < 4; ++q) {
        pa[q] = 4 * swzQ(4 * t + q);
        float4 v0 = *(const float4*)(lds + pa[q]);
        float4 v1 = *(const float4*)(lds + DIM + pa[q]);
        a0[4*q+0] = v0.x; a0[4*q+1] = v0.y; a0[4*q+2] = v0.z; a0[4*q+3] = v0.w;
        a1[4*q+0] = v1.x; a1[4*q+1] = v1.y; a1[4*q+2] = v1.z; a1[4*q+3] = v1.w;
    }
    #pragma unroll
    for (int l = 0; l < 4; ++l) {
        const float4 A[4] = {T4[(l*4+0)*256 + t], T4[(l*4+1)*256 + t],
                             T4[(l*4+2)*256 + t], T4[(l*4+3)*256 + t]};
        const int st = 1 << l;
        #pragma unroll
        for (int m = 0; m < 16; ++m) {
            if (!(m & st)) {
                const int ai = inner_idx(m, l);          // compile-time
                const float c = (ai & 1) ? A[ai>>1].z : A[ai>>1].x;
                const float s = (ai & 1) ? A[ai>>1].w : A[ai>>1].y;
                rot(a0[m], a0[m + st], c, s);
                rot(a1[m], a1[m + st], c, s);
            }
        }
    }
    // write back to the same slots (own slots; no cross-thread hazard)
    #pragma unroll
    for (int q = 0; q < 4; ++q) {
        *(float4*)(lds + pa[q])       = make_float4(a0[4*q], a0[4*q+1], a0[4*q+2], a0[4*q+3]);
        *(float4*)(lds + DIM + pa[q]) = make_float4(a1[4*q], a1[4*q+1], a1[4*q+2], a1[4*q+3]);
    }
    __syncthreads();

    // ================= phase B: e = 256*hi + 16*m + lo =================
    const int hi = t & 15, lo = t >> 4;
    float d0[16], d1[16];
    int pb[16];
    #pragma unroll
    for (int m = 0; m < 16; ++m) {
        pb[m] = perm((hi << 8) + (m << 4) + lo);     // 2-way banks (free)
        d0[m] = lds[pb[m]];
        d1[m] = lds[DIM + pb[m]];
    }
    #pragma unroll
    for (int j = 0; j < 4; ++j) {
        const float4 B[4] = {T4[4096 + (j*4+0)*256 + t], T4[4096 + (j*4+1)*256 + t],
                             T4[4096 + (j*4+2)*256 + t], T4[4096 + (j*4+3)*256 + t]};
        const int st = 1 << j;
        #pragma unroll
        for (int m = 0; m < 16; ++m) {
            if (!(m & st)) {
                const int ai = inner_idx(m, j);
                const float c = (ai & 1) ? B[ai>>1].z : B[ai>>1].x;
                const float s = (ai & 1) ? B[ai>>1].w : B[ai>>1].y;
                rot(d0[m], d0[m + st], c, s);
                rot(d1[m], d1[m + st], c, s);
            }
        }
    }
    // write back to the same per-thread slots
    #pragma unroll
    for (int m = 0; m < 16; ++m) {
        lds[pb[m]]       = d0[m];
        lds[DIM + pb[m]] = d1[m];
    }
    __syncthreads();

    // ================= phase C: e = t + 256*m =================
    float g0[16], g1[16];
    #pragma unroll
    for (int m = 0; m < 16; ++m) {
        const int p = perm(t + (m << 8));            // 2-way banks (free)
        g0[m] = lds[p];
        g1[m] = lds[DIM + p];
    }
    #pragma unroll
    for (int j = 0; j < 4; ++j) {
        const float4 C[4] = {T4[8192 + (j*4+0)*256 + t], T4[8192 + (j*4+1)*256 + t],
                             T4[8192 + (j*4+2)*256 + t], T4[8192 + (j*4+3)*256 + t]};
        const int st = 1 << j;
        #pragma unroll
        for (int m = 0; m < 16; ++m) {
            if (!(m & st)) {
                const int ai = inner_idx(m, j);
                const float c = (ai & 1) ? C[ai>>1].z : C[ai>>1].x;
                const float s = (ai & 1) ? C[ai>>1].w : C[ai>>1].y;
                rot(g0[m], g0[m + st], c, s);
                rot(g1[m], g1[m + st], c, s);
            }
        }
    }
    // store: wave writes 256B contiguous per instruction
    {
        float* o0 = out + row0 * DIM + t;
        float* o1 = o0 + DIM;
        #pragma unroll
        for (int m = 0; m < 16; ++m) {
            o0[m << 8] = g0[m];
            o1[m << 8] = g1[m];
        }
    }
}

extern "C" void kernel_launch(void* const* d_in, const int* in_sizes, int n_in,
                              void* d_out, int out_size, void* d_ws, size_t ws_size,
                              hipStream_t stream) {
    (void)in_sizes; (void)n_in; (void)out_size; (void)ws_size;
    const float* x      = (const float*)d_in[0];
    const float* angles = (const float*)d_in[1];
    float* out = (float*)d_out;

    const int n = LAYERS * NANG;                    // 24576 angles, 192 KiB table
    cs_kernel<<<(n + 255) / 256, 256, 0, stream>>>(angles, (float2*)d_ws, n);
    butterfly_kernel<<<BATCH / 2, 256, 0, stream>>>(x, (const float4*)d_ws, out);
}